// Round 11
// baseline (206.149 us; speedup 1.0000x reference)
//
#include <hip/hip_runtime.h>
#include <math.h>

#define S 8192
#define E 64
#define CAP 256
static const long long NOUT = (long long)S * E * CAP;  // 134,217,728 elems per output
static const long long NQ   = (2 * NOUT) / 4;          // 67,108,864 float4s total

typedef float f32x4 __attribute__((ext_vector_type(4)));

// ---------------------------------------------------------------------------
// Kernel A: per-row fp32 softmax + top-1/top-2 selection.
// One wave (64 lanes) per row; lane == expert id. 4 rows per block.
// Packs i1|i2<<16 into one word to halve the rank kernel's load traffic.
// ---------------------------------------------------------------------------
__global__ void softmax_top2(const float* __restrict__ in,
                             int* __restrict__ pk,
                             float* __restrict__ w1, float* __restrict__ w2) {
    const int lane = threadIdx.x;          // 0..63, == expert id
    const int row  = blockIdx.x * 4 + threadIdx.y;

    float x = in[row * E + lane];

    float mx = x;
    #pragma unroll
    for (int o = 32; o > 0; o >>= 1) mx = fmaxf(mx, __shfl_xor(mx, o));

    float p = __expf(x - mx);
    float sum = p;
    #pragma unroll
    for (int o = 32; o > 0; o >>= 1) sum += __shfl_xor(sum, o);
    float prob = p / sum;

    // argmax on x (monotonic w.r.t. softmax), first-index tie-break
    float v = x; int idx = lane;
    #pragma unroll
    for (int o = 32; o > 0; o >>= 1) {
        float ov = __shfl_xor(v, o);
        int   oi = __shfl_xor(idx, o);
        if (ov > v || (ov == v && oi < idx)) { v = ov; idx = oi; }
    }
    const int i1 = idx;

    float x2 = (lane == i1) ? -INFINITY : x;
    v = x2; idx = lane;
    #pragma unroll
    for (int o = 32; o > 0; o >>= 1) {
        float ov = __shfl_xor(v, o);
        int   oi = __shfl_xor(idx, o);
        if (ov > v || (ov == v && oi < idx)) { v = ov; idx = oi; }
    }
    const int i2 = idx;

    const float pw1 = __shfl(prob, i1);
    const float pw2 = __shfl(prob, i2);

    if (lane == 0) {
        pk[row] = i1 | (i2 << 16);
        w1[row] = pw1;
        w2[row] = pw2;
    }
}

// ---------------------------------------------------------------------------
// Kernel B: flat zero-fill. Same proven 1-store-per-thread shape, but
// 1024-thread workgroups (65,536 blocks instead of 262,144) to cut CP
// dispatch ramp. Occupancy unchanged (16 waves x 2 blocks/CU = 32 waves).
// ---------------------------------------------------------------------------
__global__ __launch_bounds__(1024) void fill_zero(f32x4* __restrict__ out) {
    const size_t i = (size_t)blockIdx.x * 1024 + threadIdx.x;
    const f32x4 z = {0.f, 0.f, 0.f, 0.f};
    out[i] = z;
}

// ---------------------------------------------------------------------------
// Kernel C: fused rank + scatter, 16 waves per expert block (1024 thr).
// Wave w owns tokens [w*512, (w+1)*512). Phase 1: per-wave match counts.
// Phase 2 (after LDS exchange): exclusive base per wave, ballot-prefix
// ranks, direct scatter of the <=2 entries per matched token.
// ---------------------------------------------------------------------------
__global__ __launch_bounds__(1024) void rank_scatter(
        const int* __restrict__ pk,
        const float* __restrict__ w1, const float* __restrict__ w2,
        float* __restrict__ out) {
    const int e    = blockIdx.x;
    const int lane = threadIdx.x & 63;
    const int w    = threadIdx.x >> 6;        // wave 0..15
    const int seg  = S / 16;                  // 512 tokens per wave
    const int t0w  = w * seg;
    const unsigned long long below = (1ULL << lane) - 1ULL;

    __shared__ int c1s[16], c2s[16];

    // phase 1: per-wave match counts (1 packed load per iter)
    int c1 = 0, c2 = 0;
    #pragma unroll 4
    for (int t0 = t0w; t0 < t0w + seg; t0 += 64) {
        const int p = pk[t0 + lane];
        c1 += __popcll(__ballot((p & 0xffff) == e));
        c2 += __popcll(__ballot((p >> 16) == e));
    }
    if (lane == 0) { c1s[w] = c1; c2s[w] = c2; }
    __syncthreads();

    int tot1 = 0;
    #pragma unroll
    for (int k = 0; k < 16; ++k) tot1 += c1s[k];
    int off1 = 0, off2 = tot1;                 // rank2 offset by total top1 count
    for (int k = 0; k < w; ++k) { off1 += c1s[k]; off2 += c2s[k]; }

    // phase 2: ballot-prefix ranks + direct scatter
    int base = off1;
    #pragma unroll 4
    for (int t0 = t0w; t0 < t0w + seg; t0 += 64) {
        const int t = t0 + lane;
        const bool hit = (pk[t] & 0xffff) == e;
        const unsigned long long m = __ballot(hit);
        if (hit) {
            const int r = base + __popcll(m & below);
            if (r < CAP) {
                const float v = w1[t];
                const long long off = (long long)t * (E * CAP) + e * CAP + r;
                out[off]        = v;
                out[NOUT + off] = (v != 0.0f) ? 1.0f : 0.0f;
            }
        }
        base += __popcll(m);
    }
    base = off2;
    #pragma unroll 4
    for (int t0 = t0w; t0 < t0w + seg; t0 += 64) {
        const int t = t0 + lane;
        const bool hit = (pk[t] >> 16) == e;
        const unsigned long long m = __ballot(hit);
        if (hit) {
            const int r = base + __popcll(m & below);
            if (r < CAP) {
                const float v = w2[t];
                const long long off = (long long)t * (E * CAP) + e * CAP + r;
                out[off]        = v;
                out[NOUT + off] = (v != 0.0f) ? 1.0f : 0.0f;
            }
        }
        base += __popcll(m);
    }
}

extern "C" void kernel_launch(void* const* d_in, const int* in_sizes, int n_in,
                              void* d_out, int out_size, void* d_ws, size_t ws_size,
                              hipStream_t stream) {
    const float* in = (const float*)d_in[0];
    float* out = (float*)d_out;

    // workspace layout (8192 each): pk, w1, w2
    int*   pk = (int*)d_ws;
    float* w1 = (float*)(pk + S);
    float* w2 = w1 + S;

    softmax_top2<<<S / 4, dim3(64, 4), 0, stream>>>(in, pk, w1, w2);
    fill_zero<<<(int)(NQ / 1024), 1024, 0, stream>>>((f32x4*)out);
    rank_scatter<<<E, 1024, 0, stream>>>(pk, w1, w2, out);
}

// Round 12
// 187.071 us; speedup vs baseline: 1.1020x; 1.1020x over previous
//
#include <hip/hip_runtime.h>
#include <math.h>

#define S 8192
#define E 64
#define CAP 256
static const long long NOUT = (long long)S * E * CAP;  // 134,217,728 elems per output
static const long long NQ   = (2 * NOUT) / 4;          // 67,108,864 float4s total

typedef float f32x4 __attribute__((ext_vector_type(4)));

// ---------------------------------------------------------------------------
// Kernel A: per-row fp32 softmax + top-1/top-2 selection.
// One wave (64 lanes) per row; lane == expert id. 4 rows per block.
// Packs i1|i2<<16 into one word to halve the rank kernel's load traffic.
// ---------------------------------------------------------------------------
__global__ void softmax_top2(const float* __restrict__ in,
                             int* __restrict__ pk,
                             float* __restrict__ w1, float* __restrict__ w2) {
    const int lane = threadIdx.x;          // 0..63, == expert id
    const int row  = blockIdx.x * 4 + threadIdx.y;

    float x = in[row * E + lane];

    float mx = x;
    #pragma unroll
    for (int o = 32; o > 0; o >>= 1) mx = fmaxf(mx, __shfl_xor(mx, o));

    float p = __expf(x - mx);
    float sum = p;
    #pragma unroll
    for (int o = 32; o > 0; o >>= 1) sum += __shfl_xor(sum, o);
    float prob = p / sum;

    // argmax on x (monotonic w.r.t. softmax), first-index tie-break
    float v = x; int idx = lane;
    #pragma unroll
    for (int o = 32; o > 0; o >>= 1) {
        float ov = __shfl_xor(v, o);
        int   oi = __shfl_xor(idx, o);
        if (ov > v || (ov == v && oi < idx)) { v = ov; idx = oi; }
    }
    const int i1 = idx;

    float x2 = (lane == i1) ? -INFINITY : x;
    v = x2; idx = lane;
    #pragma unroll
    for (int o = 32; o > 0; o >>= 1) {
        float ov = __shfl_xor(v, o);
        int   oi = __shfl_xor(idx, o);
        if (ov > v || (ov == v && oi < idx)) { v = ov; idx = oi; }
    }
    const int i2 = idx;

    const float pw1 = __shfl(prob, i1);
    const float pw2 = __shfl(prob, i2);

    if (lane == 0) {
        pk[row] = i1 | (i2 << 16);
        w1[row] = pw1;
        w2[row] = pw2;
    }
}

// ---------------------------------------------------------------------------
// Kernel B: flat zero-fill, rocclr-fillBuffer shape: ONE dwordx4 store per
// thread, 256-thread blocks, flat 262,144-block grid, no loop.
// Measured 5.97 TB/s end-to-end — parity with rocclr fill at this buffer
// size. All probed variants slower: 4 stores/thread 5.3 TB/s (R9),
// grid-stride loop 4.3 TB/s (R5), 1024-thr blocks 5.4 TB/s (R11),
// NT stores -9 µs (R3/R4), fused table-patch +30 µs (R7).
// ---------------------------------------------------------------------------
__global__ __launch_bounds__(256) void fill_zero(f32x4* __restrict__ out) {
    const size_t i = (size_t)blockIdx.x * 256 + threadIdx.x;
    const f32x4 z = {0.f, 0.f, 0.f, 0.f};
    out[i] = z;
}

// ---------------------------------------------------------------------------
// Kernel C: fused rank + scatter, 16 waves per expert block (1024 thr).
// Wave w owns tokens [w*512, (w+1)*512). Phase 1: per-wave match counts.
// Phase 2 (after LDS exchange): exclusive base per wave, ballot-prefix
// ranks, direct scatter of the <=2 entries per matched token.
// ---------------------------------------------------------------------------
__global__ __launch_bounds__(1024) void rank_scatter(
        const int* __restrict__ pk,
        const float* __restrict__ w1, const float* __restrict__ w2,
        float* __restrict__ out) {
    const int e    = blockIdx.x;
    const int lane = threadIdx.x & 63;
    const int w    = threadIdx.x >> 6;        // wave 0..15
    const int seg  = S / 16;                  // 512 tokens per wave
    const int t0w  = w * seg;
    const unsigned long long below = (1ULL << lane) - 1ULL;

    __shared__ int c1s[16], c2s[16];

    // phase 1: per-wave match counts (1 packed load per iter)
    int c1 = 0, c2 = 0;
    #pragma unroll 4
    for (int t0 = t0w; t0 < t0w + seg; t0 += 64) {
        const int p = pk[t0 + lane];
        c1 += __popcll(__ballot((p & 0xffff) == e));
        c2 += __popcll(__ballot((p >> 16) == e));
    }
    if (lane == 0) { c1s[w] = c1; c2s[w] = c2; }
    __syncthreads();

    int tot1 = 0;
    #pragma unroll
    for (int k = 0; k < 16; ++k) tot1 += c1s[k];
    int off1 = 0, off2 = tot1;                 // rank2 offset by total top1 count
    for (int k = 0; k < w; ++k) { off1 += c1s[k]; off2 += c2s[k]; }

    // phase 2: ballot-prefix ranks + direct scatter
    int base = off1;
    #pragma unroll 4
    for (int t0 = t0w; t0 < t0w + seg; t0 += 64) {
        const int t = t0 + lane;
        const bool hit = (pk[t] & 0xffff) == e;
        const unsigned long long m = __ballot(hit);
        if (hit) {
            const int r = base + __popcll(m & below);
            if (r < CAP) {
                const float v = w1[t];
                const long long off = (long long)t * (E * CAP) + e * CAP + r;
                out[off]        = v;
                out[NOUT + off] = (v != 0.0f) ? 1.0f : 0.0f;
            }
        }
        base += __popcll(m);
    }
    base = off2;
    #pragma unroll 4
    for (int t0 = t0w; t0 < t0w + seg; t0 += 64) {
        const int t = t0 + lane;
        const bool hit = (pk[t] >> 16) == e;
        const unsigned long long m = __ballot(hit);
        if (hit) {
            const int r = base + __popcll(m & below);
            if (r < CAP) {
                const float v = w2[t];
                const long long off = (long long)t * (E * CAP) + e * CAP + r;
                out[off]        = v;
                out[NOUT + off] = (v != 0.0f) ? 1.0f : 0.0f;
            }
        }
        base += __popcll(m);
    }
}

extern "C" void kernel_launch(void* const* d_in, const int* in_sizes, int n_in,
                              void* d_out, int out_size, void* d_ws, size_t ws_size,
                              hipStream_t stream) {
    const float* in = (const float*)d_in[0];
    float* out = (float*)d_out;

    // workspace layout (8192 each): pk, w1, w2
    int*   pk = (int*)d_ws;
    float* w1 = (float*)(pk + S);
    float* w2 = w1 + S;

    softmax_top2<<<S / 4, dim3(64, 4), 0, stream>>>(in, pk, w1, w2);
    fill_zero<<<(int)(NQ / 256), 256, 0, stream>>>((f32x4*)out);
    rank_scatter<<<E, 1024, 0, stream>>>(pk, w1, w2, out);
}